// Round 14
// baseline (267.722 us; speedup 1.0000x reference)
//
#include <hip/hip_runtime.h>
#include <hip/hip_bf16.h>

#define L_SEQ 2048
#define HIDN  1024
#define NH    16
#define DHD   64
#define QKV_P 3200   // padded GEMM N: 3072 qkv + 16 dt rows + 112 clamp-pad
#define QC_S  2048   // qc stride: Q(1024) + K(1024); V goes to vt
#define LP    72     // LDS row pitch (elems): 144B = 16B-aligned rows

typedef float f4 __attribute__((ext_vector_type(4)));
typedef __bf16 bf16x8 __attribute__((ext_vector_type(8)));
typedef _Float16 half8 __attribute__((ext_vector_type(8)));

union H8 {
  half8 h;
  uint4 u4;
};

__device__ __forceinline__ float b2f(unsigned short u) {
  union { unsigned int i; float f; } c; c.i = ((unsigned int)u) << 16; return c.f;
}
__device__ __forceinline__ unsigned short f2b(float f) {
  union { float f; unsigned int i; } c; c.f = f;
  unsigned int r = c.i + 0x7FFFu + ((c.i >> 16) & 1u);
  return (unsigned short)(r >> 16);
}
__device__ __forceinline__ unsigned short f2h(float f) {
  union { _Float16 h; unsigned short u; } c; c.h = (_Float16)f; return c.u;
}
// scalar param load under dtype flag (bit-identical to old prep conversion)
__device__ __forceinline__ float ldp(const void* p, int i, int f) {
  return f ? ((const float*)p)[i] : b2f(((const unsigned short*)p)[i]);
}
// load 8 elems as bf16 (uint4), converting from fp32 when f==1
__device__ __forceinline__ uint4 ld8cvt(const void* base, size_t eoff, int f) {
  if (f) {
    const float* p = (const float*)base + eoff;
    f4 v0 = *(const f4*)p, v1 = *(const f4*)(p + 4);
    uint4 r;
    r.x = (unsigned)f2b(v0[0]) | ((unsigned)f2b(v0[1]) << 16);
    r.y = (unsigned)f2b(v0[2]) | ((unsigned)f2b(v0[3]) << 16);
    r.z = (unsigned)f2b(v1[0]) | ((unsigned)f2b(v1[1]) << 16);
    r.w = (unsigned)f2b(v1[2]) | ((unsigned)f2b(v1[3]) << 16);
    return r;
  }
  return *(const uint4*)((const unsigned short*)base + eoff);
}

// ------- fused QKV+dt GEMM: C[2048][3200] = hs * [qkv_w; dt_proj_w]^T ------
// Inline dtype detect (deterministic, per-block) + inline bf16 conversion
// during reg-staging. Block (0,0) publishes *flag for downstream kernels.
// B rows >=3088 clamp to dtw row 0: garbage lands only in unused C columns.
__global__ __launch_bounds__(256) void gemm128(
    const void* __restrict__ Araw,   // hs  [2048][1024] fp32|bf16
    const void* __restrict__ Braw,   // qkv_w [3072][1024]
    const void* __restrict__ Draw,   // dt_proj_w [16][1024]
    float* __restrict__ C, int* __restrict__ flagOut)
{
  __shared__ int cnt;
  if (threadIdx.x == 0) cnt = 0;
  __syncthreads();
  {
    const unsigned short* p = (const unsigned short*)Araw;
    int c = 0;
    for (int i = threadIdx.x; i < 8192; i += 256)
      if (((p[i] >> 7) & 0xFFu) >= 140u) c++;
    atomicAdd(&cnt, c);
  }
  __syncthreads();
  const int f = (cnt >= 32) ? 1 : 0;          // 1 = fp32 inputs
  if (blockIdx.x == 0 && blockIdx.y == 0 && threadIdx.x == 0) *flagOut = f;

  __shared__ __align__(16) unsigned short As[128 * 40];
  __shared__ __align__(16) unsigned short Bs[128 * 40];
  const int t = threadIdx.x;
  const int w = t >> 6, lane = t & 63;
  const int quad = lane >> 4, l16 = lane & 15;
  const int wr = w >> 1, wc = w & 1;
  const int m0 = blockIdx.y * 128, n0 = blockIdx.x * 128;
  const int srow = t >> 1;             // 0..127
  const int scol = (t & 1) * 16;       // 0 or 16

  f4 acc[4][4];
#pragma unroll
  for (int i = 0; i < 4; ++i)
#pragma unroll
    for (int j = 0; j < 4; ++j) acc[i][j] = (f4){0.f, 0.f, 0.f, 0.f};

  const size_t aoff = (size_t)(m0 + srow) * 1024 + scol;
  const int grow = n0 + srow;
  const void* bsrc; size_t boff;
  if (grow < 3072)      { bsrc = Braw; boff = (size_t)grow * 1024 + scol; }
  else if (grow < 3088) { bsrc = Draw; boff = (size_t)(grow - 3072) * 1024 + scol; }
  else                  { bsrc = Draw; boff = (size_t)scol; }  // clamp: unused cols

  uint4 a0 = ld8cvt(Araw, aoff, f),     a1 = ld8cvt(Araw, aoff + 8, f);
  uint4 b0 = ld8cvt(bsrc, boff, f),     b1 = ld8cvt(bsrc, boff + 8, f);

  for (int k0 = 0; k0 < 1024; k0 += 32) {
    __syncthreads();
    *(uint4*)&As[srow * 40 + scol]     = a0;
    *(uint4*)&As[srow * 40 + scol + 8] = a1;
    *(uint4*)&Bs[srow * 40 + scol]     = b0;
    *(uint4*)&Bs[srow * 40 + scol + 8] = b1;
    __syncthreads();
    if (k0 + 32 < 1024) {
      a0 = ld8cvt(Araw, aoff + k0 + 32, f); a1 = ld8cvt(Araw, aoff + k0 + 40, f);
      b0 = ld8cvt(bsrc, boff + k0 + 32, f); b1 = ld8cvt(bsrc, boff + k0 + 40, f);
    }
    bf16x8 aF[4], bF[4];
#pragma unroll
    for (int i = 0; i < 4; ++i)
      aF[i] = *(const bf16x8*)&As[(wr * 64 + i * 16 + l16) * 40 + quad * 8];
#pragma unroll
    for (int j = 0; j < 4; ++j)
      bF[j] = *(const bf16x8*)&Bs[(wc * 64 + j * 16 + l16) * 40 + quad * 8];
#pragma unroll
    for (int i = 0; i < 4; ++i)
#pragma unroll
      for (int j = 0; j < 4; ++j)
        acc[i][j] = __builtin_amdgcn_mfma_f32_16x16x32_bf16(aF[i], bF[j], acc[i][j], 0, 0, 0);
  }

#pragma unroll
  for (int i = 0; i < 4; ++i)
#pragma unroll
    for (int j = 0; j < 4; ++j)
#pragma unroll
      for (int r = 0; r < 4; ++r) {
        int m = m0 + wr * 64 + i * 16 + quad * 4 + r;
        int n = n0 + wc * 64 + j * 16 + l16;
        C[(size_t)m * QKV_P + n] = acc[i][j][r];
      }
}

// ------- output GEMM: d_out = attnb(bf16) * o_w^T, B converted inline ------
__global__ __launch_bounds__(256) void gemm_out(
    const unsigned short* __restrict__ A,      // attnb bf16 [2048][1024]
    const void* __restrict__ Braw,             // o_w [1024][1024] fp32|bf16
    void* __restrict__ Cv, const int* __restrict__ flag)
{
  __shared__ __align__(16) short As[64 * 40];
  __shared__ __align__(16) short Bs[64 * 40];
  const int f = *flag;
  const int t = threadIdx.x;
  const int wave = t >> 6, lane = t & 63;
  const int quad = lane >> 4, l16 = lane & 15;
  const int m0 = blockIdx.y * 64, n0 = blockIdx.x * 64;
  const int srow = t >> 2, scol = (t & 3) * 8;
  f4 acc[4];
#pragma unroll
  for (int i = 0; i < 4; ++i) acc[i] = (f4){0.f, 0.f, 0.f, 0.f};
  const unsigned short* ap = A + (size_t)(m0 + srow) * HIDN + scol;
  const size_t boff = (size_t)(n0 + srow) * HIDN + scol;
  for (int k0 = 0; k0 < HIDN; k0 += 32) {
    uint4 av = *(const uint4*)(ap + k0);
    uint4 bv = ld8cvt(Braw, boff + k0, f);
    __syncthreads();
    *(uint4*)&As[srow * 40 + scol] = av;
    *(uint4*)&Bs[srow * 40 + scol] = bv;
    __syncthreads();
    bf16x8 af = *(const bf16x8*)&As[(wave * 16 + l16) * 40 + quad * 8];
#pragma unroll
    for (int nt = 0; nt < 4; ++nt) {
      bf16x8 bf = *(const bf16x8*)&Bs[(nt * 16 + l16) * 40 + quad * 8];
      acc[nt] = __builtin_amdgcn_mfma_f32_16x16x32_bf16(af, bf, acc[nt], 0, 0, 0);
    }
  }
#pragma unroll
  for (int nt = 0; nt < 4; ++nt) {
#pragma unroll
    for (int r = 0; r < 4; ++r) {
      int m = m0 + wave * 16 + quad * 4 + r;
      int n = n0 + nt * 16 + l16;
      if (f) ((float*)Cv)[(size_t)m * HIDN + n] = acc[nt][r];
      else   ((unsigned short*)Cv)[(size_t)m * HIDN + n] = f2b(acc[nt][r]);
    }
  }
}

// ------- fused conv + cumsum (params read inline from originals):
//   blocks <4096:      Q/K conv elementwise -> qc [L][2048]
//   blocks 4096..4607: V conv + inline-dt scale + LDS transpose -> vt
//   blocks 4608..4623: per-head A cumsum -> Acum
__global__ __launch_bounds__(256) void conv_kernel(
    const float* __restrict__ qkvf,
    const void* qw, const void* qb, const void* kw, const void* kb,
    const void* vw, const void* vb, const void* dtb, const void* dpb,
    const void* al, const int* __restrict__ flag,
    unsigned short* __restrict__ qc, unsigned short* __restrict__ vt,
    float* __restrict__ Ac)
{
  const int f = *flag;
  if (blockIdx.x < 4096) {
    const int idx = blockIdx.x * 256 + threadIdx.x;
    const int l = idx >> 9;                 // / 512
    const int c = (idx & 511) * 4;          // 0..2044
    f4 xc = *(const f4*)&qkvf[(size_t)l * QKV_P + c];
    f4 xp = (f4){0.f, 0.f, 0.f, 0.f};
    if (l > 0) xp = *(const f4*)&qkvf[(size_t)(l - 1) * QKV_P + c];
    const void* w; const void* b; int cb;
    if (c < HIDN) { w = qw; b = qb; cb = c; }
    else          { w = kw; b = kb; cb = c - HIDN; }
    f4 o;
#pragma unroll
    for (int j = 0; j < 4; ++j)
      o[j] = ldp(b, cb + j, f) + xp[j] * ldp(w, (cb + j) * 2, f)
           + xc[j] * ldp(w, (cb + j) * 2 + 1, f);
    ushort4 st;
    st.x = f2h(o[0]); st.y = f2h(o[1]); st.z = f2h(o[2]); st.w = f2h(o[3]);
    *(ushort4*)&qc[(size_t)l * QC_S + c] = st;
  } else if (blockIdx.x < 4608) {
    __shared__ __align__(16) unsigned short Ts[64 * 68];
    const int bv = blockIdx.x - 4096;       // 0..511
    const int h = bv & 15;
    const int lt0 = bv >> 4;                // 0..31
    const int t = threadIdx.x;
    const int srow = t >> 2, cc = t & 3;
    const int l = lt0 * 64 + srow;
    const int cb = h * 64 + cc * 16;        // V-channel base (0..1023)
    // inline dt = softplus(qkvf[l][3072+h] + dt_proj_b + dt_bias)
    const float z = qkvf[(size_t)l * QKV_P + 3072 + h]
                  + ldp(dpb, h, f) + ldp(dtb, h, f);
    const float dtv = (z > 20.f) ? z : log1pf(expf(z));
    const float* xcp = &qkvf[(size_t)l * QKV_P + 2048 + cb];
    const float* xpp = &qkvf[(size_t)(l - 1) * QKV_P + 2048 + cb];
    unsigned short o16[16];
#pragma unroll
    for (int g = 0; g < 4; ++g) {
      f4 xc = *(const f4*)(xcp + g * 4);
      f4 xp = (f4){0.f, 0.f, 0.f, 0.f};
      if (l > 0) xp = *(const f4*)(xpp + g * 4);
#pragma unroll
      for (int j = 0; j < 4; ++j) {
        const int ch = cb + g * 4 + j;
        float o = ldp(vb, ch, f) + xp[j] * ldp(vw, ch * 2, f)
                + xc[j] * ldp(vw, ch * 2 + 1, f);
        o16[g * 4 + j] = f2h(o * dtv);
      }
    }
    *(uint4*)&Ts[srow * 68 + cc * 16]     = *(const uint4*)&o16[0];
    *(uint4*)&Ts[srow * 68 + cc * 16 + 8] = *(const uint4*)&o16[8];
    __syncthreads();
    __align__(16) unsigned short o[16];
#pragma unroll
    for (int j = 0; j < 16; ++j) o[j] = Ts[(cc * 16 + j) * 68 + srow];
    unsigned short* op = vt + ((size_t)h * DHD + srow) * L_SEQ + lt0 * 64 + cc * 16;
    *(uint4*)op = *(const uint4*)&o[0];
    *(uint4*)(op + 8) = *(const uint4*)&o[8];
  } else {
    const int h = blockIdx.x - 4608;
    const int lane = threadIdx.x;
    if (lane < 64) {
      const int base = lane * 32;
      const float dpbv = ldp(dpb, h, f), dtbv = ldp(dtb, h, f);
      const float nal = -expf(ldp(al, h, f));
      float Av[32];
      float run = 0.f;
#pragma unroll
      for (int i = 0; i < 32; ++i) {
        const int l = base + i;
        float z = qkvf[(size_t)l * QKV_P + 3072 + h] + dpbv + dtbv;
        float dtv = (z > 20.f) ? z : log1pf(expf(z));
        Av[i] = nal * dtv;
        run += Av[i];
      }
      float incl = run;
#pragma unroll
      for (int off = 1; off < 64; off <<= 1) {
        float n = __shfl_up(incl, off);
        if (lane >= off) incl += n;
      }
      float r2 = incl - run;
#pragma unroll
      for (int i = 0; i < 32; ++i) {
        r2 += Av[i];
        Ac[h * L_SEQ + base + i] = r2;
      }
    }
  }
}

// ------- gated causal attention, split-m halves, fp32 partials -------------
// grid 1024: n -> r=n&7 (XCD under RR%8), hh=(n>>3)&1, k=n>>4 in [0,64):
//   h = r+8*hh; lt = 31-(k>>1) (biggest halves first: LPT greedy);
//   s = k&1 selects m-half. Gate sum over m is linear -> halves add exactly.
__global__ __launch_bounds__(256) void attn_kernel(
    const unsigned short* __restrict__ qc,     // fp16 [L][2048] (Q,K)
    const unsigned short* __restrict__ vt,     // fp16 [NH][DHD][L] (V^T)
    const float* __restrict__ Ac,              // [NH][L]
    const void* __restrict__ ordc, const int* __restrict__ flag,
    float* __restrict__ po)                    // fp32 [2][L][1024] partials
{
  const int n  = blockIdx.x;
  const int r_ = n & 7;
  const int hh = (n >> 3) & 1;
  const int k_ = n >> 4;                   // 0..63
  const int h  = r_ + 8 * hh;
  const int lt = 31 - (k_ >> 1);
  const int s_ = k_ & 1;
  const int nT = lt + 1;
  const int mS = s_ ? ((nT + 1) >> 1) : 0;
  const int mE = s_ ? nT : ((nT + 1) >> 1);

  const int t  = threadIdx.x;
  const int w    = t >> 6;
  const int lane = t & 63;
  const int l16  = lane & 15;
  const int quad = lane >> 4;
  const int srow = t >> 2;
  const int cc   = t & 3;

  __shared__ __align__(16) unsigned short K_lds[2][64 * LP];  // K[m][d]
  __shared__ __align__(16) unsigned short V_lds[2][64 * LP];  // V^T[d][m]
  __shared__ __align__(16) unsigned short S_lds[64 * LP];     // S[l][m]

  const int l0 = lt * 64;
  const float rc = 1.0f / ldp(ordc, h, *flag);
  const float* Acp = Ac + h * L_SEQ;

  H8 qf0, qf1;
  {
    const unsigned short* qp =
        qc + (size_t)(l0 + w * 16 + l16) * QC_S + h * DHD + quad * 8;
    qf0.u4 = *(const uint4*)qp;
    qf1.u4 = *(const uint4*)(qp + 32);
  }
  float alv[4];
#pragma unroll
  for (int r = 0; r < 4; ++r) alv[r] = Acp[l0 + w * 16 + quad * 4 + r];

  f4 acc[4];
#pragma unroll
  for (int i = 0; i < 4; ++i) acc[i] = (f4){0.f, 0.f, 0.f, 0.f};

  const unsigned short* kgp =
      qc + (size_t)srow * QC_S + HIDN + h * DHD + cc * 16;
  const unsigned short* vgp =
      vt + ((size_t)h * DHD + srow) * L_SEQ + cc * 16;
  const int swo = srow * LP + cc * 16;

  if (mS < mE) {                           // block-uniform guard
    uint4 k0v = *(const uint4*)(kgp + (size_t)mS * 64 * QC_S);
    uint4 k1v = *(const uint4*)(kgp + (size_t)mS * 64 * QC_S + 8);
    uint4 v0v = *(const uint4*)(vgp + (size_t)mS * 64);
    uint4 v1v = *(const uint4*)(vgp + (size_t)mS * 64 + 8);
    float amv[4];
#pragma unroll
    for (int nt = 0; nt < 4; ++nt) amv[nt] = Acp[mS * 64 + nt * 16 + l16];

    *(uint4*)&K_lds[0][swo]     = k0v;
    *(uint4*)&K_lds[0][swo + 8] = k1v;
    *(uint4*)&V_lds[0][swo]     = v0v;
    *(uint4*)&V_lds[0][swo + 8] = v1v;
    __syncthreads();

    int cur = 0;
    for (int it = mS; it < mE; ++it) {
      uint4 nk0 = k0v, nk1 = k1v, nv0 = v0v, nv1 = v1v;
      float namv[4];
      const bool more = (it + 1 < mE);
      if (more) {
        const unsigned short* kp = kgp + (size_t)(it + 1) * 64 * QC_S;
        const unsigned short* vp = vgp + (size_t)(it + 1) * 64;
        nk0 = *(const uint4*)kp; nk1 = *(const uint4*)(kp + 8);
        nv0 = *(const uint4*)vp; nv1 = *(const uint4*)(vp + 8);
#pragma unroll
        for (int nt = 0; nt < 4; ++nt)
          namv[nt] = Acp[(it + 1) * 64 + nt * 16 + l16];
      }

      // ---- QK^T (b128 fragment reads) ----
      f4 s[4];
#pragma unroll
      for (int i = 0; i < 4; ++i) s[i] = (f4){0.f, 0.f, 0.f, 0.f};
      __builtin_amdgcn_s_setprio(1);
#pragma unroll
      for (int ks = 0; ks < 2; ++ks) {
        H8 qk = ks ? qf1 : qf0;
#pragma unroll
        for (int nt = 0; nt < 4; ++nt) {
          H8 kf;
          kf.u4 = *(const uint4*)&K_lds[cur][(nt * 16 + l16) * LP + ks * 32 + quad * 8];
          s[nt] = __builtin_amdgcn_mfma_f32_16x16x32_f16(qk.h, kf.h, s[nt], 0, 0, 0);
        }
      }
      __builtin_amdgcn_s_setprio(0);
      // ---- gate + S write (causal compare only on diagonal tile) ----
      const int m0 = it * 64;
      if (it == lt) {
#pragma unroll
        for (int nt = 0; nt < 4; ++nt) {
          const int mg = m0 + nt * 16 + l16;
          const float am = amv[nt];
#pragma unroll
          for (int r = 0; r < 4; ++r) {
            const int lg = l0 + w * 16 + quad * 4 + r;
            float val = (mg <= lg) ? s[nt][r] * __expf(alv[r] - am) * rc : 0.0f;
            S_lds[(w * 16 + quad * 4 + r) * LP + nt * 16 + l16] = f2h(val);
          }
        }
      } else {
#pragma unroll
        for (int nt = 0; nt < 4; ++nt) {
          const float am = amv[nt];
#pragma unroll
          for (int r = 0; r < 4; ++r) {
            float val = s[nt][r] * __expf(alv[r] - am) * rc;
            S_lds[(w * 16 + quad * 4 + r) * LP + nt * 16 + l16] = f2h(val);
          }
        }
      }
      // ---- PV (wave-private S rows; b128 reads) ----
      __builtin_amdgcn_s_setprio(1);
#pragma unroll
      for (int ks = 0; ks < 2; ++ks) {
        H8 sa;
        sa.u4 = *(const uint4*)&S_lds[(w * 16 + l16) * LP + ks * 32 + quad * 8];
#pragma unroll
        for (int db = 0; db < 4; ++db) {
          H8 vb;
          vb.u4 = *(const uint4*)&V_lds[cur][(db * 16 + l16) * LP + ks * 32 + quad * 8];
          acc[db] = __builtin_amdgcn_mfma_f32_16x16x32_f16(sa.h, vb.h, acc[db], 0, 0, 0);
        }
      }
      __builtin_amdgcn_s_setprio(0);
      // ---- stage next tile (b128) + one barrier ----
      if (more) {
        unsigned short* Kl = K_lds[cur ^ 1];
        unsigned short* Vl = V_lds[cur ^ 1];
        *(uint4*)&Kl[swo]     = nk0;
        *(uint4*)&Kl[swo + 8] = nk1;
        *(uint4*)&Vl[swo]     = nv0;
        *(uint4*)&Vl[swo + 8] = nv1;
#pragma unroll
        for (int nt = 0; nt < 4; ++nt) amv[nt] = namv[nt];
        __syncthreads();
        cur ^= 1;
      }
    }
  }

  // ---- write fp32 partials (zeros if this half had no work) ----
  float* pout = po + (size_t)s_ * (L_SEQ * HIDN);
#pragma unroll
  for (int r = 0; r < 4; ++r) {
    float* op = pout + (size_t)(l0 + w * 16 + quad * 4 + r) * HIDN + h * DHD + l16;
#pragma unroll
    for (int db = 0; db < 4; ++db)
      op[db * 16] = acc[db][r];
  }
}

// ------- reduce: po0+po1, RMSNorm over d=64, bf16 store --------------------
__global__ __launch_bounds__(256) void reduce_kernel(
    const float* __restrict__ po, const void* __restrict__ nw,
    const int* __restrict__ flag, unsigned short* __restrict__ attn_out)
{
  const int f = *flag;
  const int l = blockIdx.x;
  const int t = threadIdx.x;
  const int col = t * 4;
  const float* p0 = po + (size_t)l * HIDN + col;
  const float* p1 = p0 + (size_t)L_SEQ * HIDN;
  f4 a = *(const f4*)p0;
  f4 b = *(const f4*)p1;
  f4 o = a + b;
  float p = o[0] * o[0] + o[1] * o[1] + o[2] * o[2] + o[3] * o[3];
#pragma unroll
  for (int off = 1; off < 16; off <<= 1) p += __shfl_xor(p, off);
  const float rn = rsqrtf(p * (1.0f / 64.0f) + 1.1920928955078125e-07f);
  const int d0 = col & 63;
  ushort4 st;
  st.x = f2b(o[0] * rn * ldp(nw, d0, f));
  st.y = f2b(o[1] * rn * ldp(nw, d0 + 1, f));
  st.z = f2b(o[2] * rn * ldp(nw, d0 + 2, f));
  st.w = f2b(o[3] * rn * ldp(nw, d0 + 3, f));
  *(ushort4*)&attn_out[(size_t)l * HIDN + col] = st;
}

extern "C" void kernel_launch(void* const* d_in, const int* in_sizes, int n_in,
                              void* d_out, int out_size, void* d_ws, size_t ws_size,
                              hipStream_t stream)
{
  (void)in_sizes; (void)n_in; (void)out_size; (void)ws_size;
  const void* hs        = d_in[0];
  // d_in[1] = attention_mask: deterministic causal triu — handled analytically
  const void* qkv_w     = d_in[2];
  const void* q_conv_w  = d_in[3];
  const void* q_conv_b  = d_in[4];
  const void* k_conv_w  = d_in[5];
  const void* k_conv_b  = d_in[6];
  const void* v_conv_w  = d_in[7];
  const void* v_conv_b  = d_in[8];
  const void* norm_w    = d_in[9];
  const void* A_log     = d_in[10];
  const void* dt_bias   = d_in[11];
  const void* dt_proj_w = d_in[12];
  const void* dt_proj_b = d_in[13];
  const void* o_w       = d_in[14];
  const void* ordc      = d_in[15];

  char* ws = (char*)d_ws;
  int* flag             = (int*)ws;                              // @0 (256B)
  float* qkvf           = (float*)(ws + 256);                    // 26,214,400 ([2048][3200] f32)
  unsigned short* qc_h  = (unsigned short*)(ws + 26214656);      // 8,388,608 ([2048][2048] f16)
  unsigned short* vt_h  = (unsigned short*)(ws + 34603264);      // 4,194,304
  float* Acum           = (float*)(ws + 38797568);               // 131,072
  unsigned short* attnb = (unsigned short*)(ws + 38928640);      // 4,194,304
  float* po             = (float*)(ws + 43122944);               // 16,777,216 ([2][2048][1024] f32)

  gemm128<<<dim3(QKV_P / 128, L_SEQ / 128), 256, 0, stream>>>(
      hs, qkv_w, dt_proj_w, qkvf, flag);
  conv_kernel<<<4096 + 512 + 16, 256, 0, stream>>>(
      qkvf, q_conv_w, q_conv_b, k_conv_w, k_conv_b, v_conv_w, v_conv_b,
      dt_bias, dt_proj_b, A_log, flag, qc_h, vt_h, Acum);
  attn_kernel<<<1024, 256, 0, stream>>>(qc_h, vt_h, Acum, ordc, flag, po);
  reduce_kernel<<<L_SEQ, 256, 0, stream>>>(po, norm_w, flag, attnb);
  gemm_out<<<dim3(HIDN / 64, L_SEQ / 64), 256, 0, stream>>>(
      attnb, o_w, d_out, flag);
}

// Round 15
// 220.694 us; speedup vs baseline: 1.2131x; 1.2131x over previous
//
#include <hip/hip_runtime.h>
#include <hip/hip_bf16.h>

#define L_SEQ 2048
#define HIDN  1024
#define NH    16
#define DHD   64
#define QKV_P 3200   // padded GEMM N: 3072 qkv + 16 dt rows + 112 pad
#define QC_S  2048   // qc stride: Q(1024) + K(1024); V goes to vt
#define LP    72     // LDS row pitch (elems): 144B = 16B-aligned rows

typedef float f4 __attribute__((ext_vector_type(4)));
typedef __bf16 bf16x8 __attribute__((ext_vector_type(8)));
typedef _Float16 half8 __attribute__((ext_vector_type(8)));

union H8 {
  half8 h;
  uint4 u4;
};

__device__ __forceinline__ float b2f(unsigned short u) {
  union { unsigned int i; float f; } c; c.i = ((unsigned int)u) << 16; return c.f;
}
__device__ __forceinline__ unsigned short f2b(float f) {
  union { float f; unsigned int i; } c; c.f = f;
  unsigned int r = c.i + 0x7FFFu + ((c.i >> 16) & 1u);
  return (unsigned short)(r >> 16);
}
__device__ __forceinline__ unsigned short f2h(float f) {
  union { _Float16 h; unsigned short u; } c; c.h = (_Float16)f; return c.u;
}

// ------------- fused prep: dtype detect + canonicalize all params ----------
// One-time conversion amortizes across GEMM panel reuse (R14 lesson).
// qkvw_b is [3200][1024] bf16: rows 0-3071 = qkv_w, 3072-3087 = dt_proj_w,
// 3088-3199 = zeros. smallf layout: qw@0(2048) qb@2048(1024) kw@3072(2048)
// kb@5120(1024) vw@6144(2048) vb@8192(1024) nw@9216(64) al@9280(16)
// dt_bias@9296(16) dt_proj_b@9312(16) oc@9328(16)  total 9344
__global__ __launch_bounds__(256) void prep_kernel(
    const void* hs, const void* qkvw, const void* ow, const void* dtw,
    const void* qw, const void* qb, const void* kw, const void* kb,
    const void* vw, const void* vb, const void* nw, const void* al,
    const void* dtb, const void* dpb, const void* oc,
    unsigned short* __restrict__ hs_b, unsigned short* __restrict__ qkvw_b,
    unsigned short* __restrict__ ow_b,
    float* __restrict__ smallf, int* __restrict__ flag)
{
  __shared__ int cnt;
  if (threadIdx.x == 0) cnt = 0;
  __syncthreads();
  {
    const unsigned short* p = (const unsigned short*)hs;
    int c = 0;
    for (int i = threadIdx.x; i < 8192; i += 256)
      if (((p[i] >> 7) & 0xFFu) >= 140u) c++;
    atomicAdd(&cnt, c);
  }
  __syncthreads();
  const int f = (cnt >= 32) ? 1 : 0;          // 1 = fp32 inputs
  if (blockIdx.x == 0 && threadIdx.x == 0) *flag = f;

  const int tid = blockIdx.x * 256 + threadIdx.x;
  const int nth = gridDim.x * 256;
  // 4-elem groups: hs 524288 | qkvw 786432 | dtw 4096 | pad 28672 | ow 262144
  for (int i = tid; i < 1605632; i += nth) {
    const void* src; unsigned short* dst; int off;
    if (i < 524288)       { src = hs;   dst = hs_b;   off = i; }
    else if (i < 1310720) { src = qkvw; dst = qkvw_b; off = i - 524288; }
    else if (i < 1314816) { src = dtw;  dst = qkvw_b + 3072 * 1024; off = i - 1310720; }
    else if (i < 1343488) {  // zero pad rows 3088-3199
      *(ushort4*)(qkvw_b + 3088 * 1024 + (i - 1314816) * 4) = (ushort4){0, 0, 0, 0};
      continue;
    }
    else                  { src = ow;   dst = ow_b;   off = i - 1343488; }
    const int e = off * 4;
    if (f) {
      f4 v = *(const f4*)((const float*)src + e);
      ushort4 o;
      o.x = f2b(v[0]); o.y = f2b(v[1]); o.z = f2b(v[2]); o.w = f2b(v[3]);
      *(ushort4*)(dst + e) = o;
    } else {
      *(uint2*)(dst + e) = *(const uint2*)((const unsigned short*)src + e);
    }
  }
  const void* ptrs[11] = {qw, qb, kw, kb, vw, vb, nw, al, dtb, dpb, oc};
  const int sizes[11] = {2048, 1024, 2048, 1024, 2048, 1024, 64, 16, 16, 16, 16};
  int off = 0;
  for (int a = 0; a < 11; ++a) {
    for (int i = tid; i < sizes[a]; i += nth)
      smallf[off + i] = f ? ((const float*)ptrs[a])[i]
                          : b2f(((const unsigned short*)ptrs[a])[i]);
    off += sizes[a];
  }
}

// ------- C = A (MxK) * B^T (NxK), bf16 in, fp32 out, 128x128 tile ---------
__global__ __launch_bounds__(256) void gemm128(
    const unsigned short* __restrict__ A, const unsigned short* __restrict__ B,
    float* __restrict__ C, int M, int N, int K)
{
  __shared__ __align__(16) unsigned short As[128 * 40];
  __shared__ __align__(16) unsigned short Bs[128 * 40];
  const int t = threadIdx.x;
  const int w = t >> 6, lane = t & 63;
  const int quad = lane >> 4, l16 = lane & 15;
  const int wr = w >> 1, wc = w & 1;
  const int m0 = blockIdx.y * 128, n0 = blockIdx.x * 128;
  const int srow = t >> 1;
  const int scol = (t & 1) * 16;

  f4 acc[4][4];
#pragma unroll
  for (int i = 0; i < 4; ++i)
#pragma unroll
    for (int j = 0; j < 4; ++j) acc[i][j] = (f4){0.f, 0.f, 0.f, 0.f};

  const unsigned short* apg = A + (size_t)(m0 + srow) * K + scol;
  const unsigned short* bpg = B + (size_t)(n0 + srow) * K + scol;
  uint4 a0 = *(const uint4*)apg,       a1 = *(const uint4*)(apg + 8);
  uint4 b0 = *(const uint4*)bpg,       b1 = *(const uint4*)(bpg + 8);

  for (int k0 = 0; k0 < K; k0 += 32) {
    __syncthreads();
    *(uint4*)&As[srow * 40 + scol]     = a0;
    *(uint4*)&As[srow * 40 + scol + 8] = a1;
    *(uint4*)&Bs[srow * 40 + scol]     = b0;
    *(uint4*)&Bs[srow * 40 + scol + 8] = b1;
    __syncthreads();
    if (k0 + 32 < K) {
      a0 = *(const uint4*)(apg + k0 + 32); a1 = *(const uint4*)(apg + k0 + 40);
      b0 = *(const uint4*)(bpg + k0 + 32); b1 = *(const uint4*)(bpg + k0 + 40);
    }
    bf16x8 aF[4], bF[4];
#pragma unroll
    for (int i = 0; i < 4; ++i)
      aF[i] = *(const bf16x8*)&As[(wr * 64 + i * 16 + l16) * 40 + quad * 8];
#pragma unroll
    for (int j = 0; j < 4; ++j)
      bF[j] = *(const bf16x8*)&Bs[(wc * 64 + j * 16 + l16) * 40 + quad * 8];
#pragma unroll
    for (int i = 0; i < 4; ++i)
#pragma unroll
      for (int j = 0; j < 4; ++j)
        acc[i][j] = __builtin_amdgcn_mfma_f32_16x16x32_bf16(aF[i], bF[j], acc[i][j], 0, 0, 0);
  }

#pragma unroll
  for (int i = 0; i < 4; ++i)
#pragma unroll
    for (int j = 0; j < 4; ++j)
#pragma unroll
      for (int r = 0; r < 4; ++r) {
        int m = m0 + wr * 64 + i * 16 + quad * 4 + r;
        int n = n0 + wc * 64 + j * 16 + l16;
        C[(size_t)m * N + n] = acc[i][j][r];
      }
}

// ---------------- C = A (MxK) * B^T (NxK), bf16 in, 64x64 tile --------------
template <int MODE>
__global__ __launch_bounds__(256) void gemm_bt(
    const unsigned short* __restrict__ A, const unsigned short* __restrict__ B,
    void* __restrict__ Cv, int M, int N, int K, const int* __restrict__ flag)
{
  __shared__ __align__(16) short As[64 * 40];
  __shared__ __align__(16) short Bs[64 * 40];
  const int t = threadIdx.x;
  const int wave = t >> 6, lane = t & 63;
  const int quad = lane >> 4, l16 = lane & 15;
  const int m0 = blockIdx.y * 64, n0 = blockIdx.x * 64;
  const int srow = t >> 2, scol = (t & 3) * 8;
  f4 acc[4];
#pragma unroll
  for (int i = 0; i < 4; ++i) acc[i] = (f4){0.f, 0.f, 0.f, 0.f};
  const unsigned short* ap = A + (size_t)(m0 + srow) * K + scol;
  const unsigned short* bp = B + (size_t)(n0 + srow) * K + scol;
  for (int k0 = 0; k0 < K; k0 += 32) {
    uint4 av = *(const uint4*)(ap + k0);
    uint4 bv = *(const uint4*)(bp + k0);
    __syncthreads();
    *(uint4*)&As[srow * 40 + scol] = av;
    *(uint4*)&Bs[srow * 40 + scol] = bv;
    __syncthreads();
    bf16x8 af = *(const bf16x8*)&As[(wave * 16 + l16) * 40 + quad * 8];
#pragma unroll
    for (int nt = 0; nt < 4; ++nt) {
      bf16x8 bf = *(const bf16x8*)&Bs[(nt * 16 + l16) * 40 + quad * 8];
      acc[nt] = __builtin_amdgcn_mfma_f32_16x16x32_bf16(af, bf, acc[nt], 0, 0, 0);
    }
  }
  const int outf32 = (MODE == 0) ? 1 : (*flag ? 1 : 0);
#pragma unroll
  for (int nt = 0; nt < 4; ++nt) {
#pragma unroll
    for (int r = 0; r < 4; ++r) {
      int m = m0 + wave * 16 + quad * 4 + r;
      int n = n0 + nt * 16 + l16;
      if (outf32) ((float*)Cv)[(size_t)m * N + n] = acc[nt][r];
      else        ((unsigned short*)Cv)[(size_t)m * N + n] = f2b(acc[nt][r]);
    }
  }
}

// ------- fused conv + cumsum:
//   blocks <4096:      Q/K conv elementwise -> qc [L][2048]
//   blocks 4096..4607: V conv + inline-dt scale + LDS transpose -> vt
//   blocks 4608..4623: per-head A cumsum -> Acum (dt recomputed inline)
__global__ __launch_bounds__(256) void conv_kernel(
    const float* __restrict__ qkvf, const float* __restrict__ smallf,
    unsigned short* __restrict__ qc, unsigned short* __restrict__ vt,
    float* __restrict__ Ac)
{
  if (blockIdx.x < 4096) {
    const int idx = blockIdx.x * 256 + threadIdx.x;
    const int l = idx >> 9;                 // / 512
    const int c = (idx & 511) * 4;          // 0..2044
    f4 xc = *(const f4*)&qkvf[(size_t)l * QKV_P + c];
    f4 xp = (f4){0.f, 0.f, 0.f, 0.f};
    if (l > 0) xp = *(const f4*)&qkvf[(size_t)(l - 1) * QKV_P + c];
    const float* w; const float* b; int cb;
    if (c < HIDN) { w = smallf;        b = smallf + 2048; cb = c; }
    else          { w = smallf + 3072; b = smallf + 5120; cb = c - HIDN; }
    f4 o;
#pragma unroll
    for (int j = 0; j < 4; ++j)
      o[j] = b[cb + j] + xp[j] * w[(cb + j) * 2] + xc[j] * w[(cb + j) * 2 + 1];
    ushort4 st;
    st.x = f2h(o[0]); st.y = f2h(o[1]); st.z = f2h(o[2]); st.w = f2h(o[3]);
    *(ushort4*)&qc[(size_t)l * QC_S + c] = st;
  } else if (blockIdx.x < 4608) {
    __shared__ __align__(16) unsigned short Ts[64 * 68];
    const int bv = blockIdx.x - 4096;       // 0..511
    const int h = bv & 15;
    const int lt0 = bv >> 4;                // 0..31
    const int t = threadIdx.x;
    const int srow = t >> 2, cc = t & 3;
    const int l = lt0 * 64 + srow;
    const int cb = h * 64 + cc * 16;        // V-channel base (0..1023)
    const float* w = smallf + 6144;
    const float* b = smallf + 8192;
    // inline dt = softplus(qkvf[l][3072+h] + dt_proj_b + dt_bias)
    const float z = qkvf[(size_t)l * QKV_P + 3072 + h]
                  + smallf[9312 + h] + smallf[9296 + h];
    const float dtv = (z > 20.f) ? z : log1pf(expf(z));
    const float* xcp = &qkvf[(size_t)l * QKV_P + 2048 + cb];
    const float* xpp = &qkvf[(size_t)(l - 1) * QKV_P + 2048 + cb];
    unsigned short o16[16];
#pragma unroll
    for (int g = 0; g < 4; ++g) {
      f4 xc = *(const f4*)(xcp + g * 4);
      f4 xp = (f4){0.f, 0.f, 0.f, 0.f};
      if (l > 0) xp = *(const f4*)(xpp + g * 4);
#pragma unroll
      for (int j = 0; j < 4; ++j) {
        const int ch = cb + g * 4 + j;
        float o = b[ch] + xp[j] * w[ch * 2] + xc[j] * w[ch * 2 + 1];
        o16[g * 4 + j] = f2h(o * dtv);
      }
    }
    *(uint4*)&Ts[srow * 68 + cc * 16]     = *(const uint4*)&o16[0];
    *(uint4*)&Ts[srow * 68 + cc * 16 + 8] = *(const uint4*)&o16[8];
    __syncthreads();
    __align__(16) unsigned short o[16];
#pragma unroll
    for (int j = 0; j < 16; ++j) o[j] = Ts[(cc * 16 + j) * 68 + srow];
    unsigned short* op = vt + ((size_t)h * DHD + srow) * L_SEQ + lt0 * 64 + cc * 16;
    *(uint4*)op = *(const uint4*)&o[0];
    *(uint4*)(op + 8) = *(const uint4*)&o[8];
  } else {
    const int h = blockIdx.x - 4608;
    const int lane = threadIdx.x;
    if (lane < 64) {
      const int base = lane * 32;
      const float dpb = smallf[9312 + h], dtb = smallf[9296 + h];
      const float nal = -expf(smallf[9280 + h]);
      float Av[32];
      float run = 0.f;
#pragma unroll
      for (int i = 0; i < 32; ++i) {
        const int l = base + i;
        float z = qkvf[(size_t)l * QKV_P + 3072 + h] + dpb + dtb;
        float dtv = (z > 20.f) ? z : log1pf(expf(z));
        Av[i] = nal * dtv;
        run += Av[i];
      }
      float incl = run;
#pragma unroll
      for (int off = 1; off < 64; off <<= 1) {
        float n = __shfl_up(incl, off);
        if (lane >= off) incl += n;
      }
      float r2 = incl - run;
#pragma unroll
      for (int i = 0; i < 32; ++i) {
        r2 += Av[i];
        Ac[h * L_SEQ + base + i] = r2;
      }
    }
  }
}

// ------- gated causal attention, split-m halves, fp32 partials -------------
// grid 1024: n -> r=n&7 (XCD under RR%8), hh=(n>>3)&1, k=n>>4 in [0,64):
//   h = r+8*hh; lt = 31-(k>>1) (BIGGEST halves dispatch first: LPT greedy);
//   s = k&1 selects m-half [0,ceil(nT/2)) or [ceil(nT/2),nT), nT=lt+1.
// Gate sum over m is linear -> halves add exactly; reduce_kernel sums +
// RMSNorm. LDS 46080B -> 3 blocks/CU.
__global__ __launch_bounds__(256) void attn_kernel(
    const unsigned short* __restrict__ qc,     // fp16 [L][2048] (Q,K)
    const unsigned short* __restrict__ vt,     // fp16 [NH][DHD][L] (V^T)
    const float* __restrict__ Ac,              // [NH][L]
    const float* __restrict__ smallf,
    float* __restrict__ po)                    // fp32 [2][L][1024] partials
{
  const int n  = blockIdx.x;
  const int r_ = n & 7;
  const int hh = (n >> 3) & 1;
  const int k_ = n >> 4;                   // 0..63
  const int h  = r_ + 8 * hh;
  const int lt = 31 - (k_ >> 1);
  const int s_ = k_ & 1;
  const int nT = lt + 1;
  const int mS = s_ ? ((nT + 1) >> 1) : 0;
  const int mE = s_ ? nT : ((nT + 1) >> 1);

  const int t  = threadIdx.x;
  const int w    = t >> 6;
  const int lane = t & 63;
  const int l16  = lane & 15;
  const int quad = lane >> 4;
  const int srow = t >> 2;
  const int cc   = t & 3;

  __shared__ __align__(16) unsigned short K_lds[2][64 * LP];  // K[m][d]
  __shared__ __align__(16) unsigned short V_lds[2][64 * LP];  // V^T[d][m]
  __shared__ __align__(16) unsigned short S_lds[64 * LP];     // S[l][m]

  const int l0 = lt * 64;
  const float rc = 1.0f / smallf[9328 + h];
  const float* Acp = Ac + h * L_SEQ;

  H8 qf0, qf1;
  {
    const unsigned short* qp =
        qc + (size_t)(l0 + w * 16 + l16) * QC_S + h * DHD + quad * 8;
    qf0.u4 = *(const uint4*)qp;
    qf1.u4 = *(const uint4*)(qp + 32);
  }
  float alv[4];
#pragma unroll
  for (int r = 0; r < 4; ++r) alv[r] = Acp[l0 + w * 16 + quad * 4 + r];

  f4 acc[4];
#pragma unroll
  for (int i = 0; i < 4; ++i) acc[i] = (f4){0.f, 0.f, 0.f, 0.f};

  const unsigned short* kgp =
      qc + (size_t)srow * QC_S + HIDN + h * DHD + cc * 16;
  const unsigned short* vgp =
      vt + ((size_t)h * DHD + srow) * L_SEQ + cc * 16;
  const int swo = srow * LP + cc * 16;

  if (mS < mE) {                           // block-uniform guard
    uint4 k0v = *(const uint4*)(kgp + (size_t)mS * 64 * QC_S);
    uint4 k1v = *(const uint4*)(kgp + (size_t)mS * 64 * QC_S + 8);
    uint4 v0v = *(const uint4*)(vgp + (size_t)mS * 64);
    uint4 v1v = *(const uint4*)(vgp + (size_t)mS * 64 + 8);
    float amv[4];
#pragma unroll
    for (int nt = 0; nt < 4; ++nt) amv[nt] = Acp[mS * 64 + nt * 16 + l16];

    *(uint4*)&K_lds[0][swo]     = k0v;
    *(uint4*)&K_lds[0][swo + 8] = k1v;
    *(uint4*)&V_lds[0][swo]     = v0v;
    *(uint4*)&V_lds[0][swo + 8] = v1v;
    __syncthreads();

    int cur = 0;
    for (int it = mS; it < mE; ++it) {
      uint4 nk0 = k0v, nk1 = k1v, nv0 = v0v, nv1 = v1v;
      float namv[4];
      const bool more = (it + 1 < mE);
      if (more) {
        const unsigned short* kp = kgp + (size_t)(it + 1) * 64 * QC_S;
        const unsigned short* vp = vgp + (size_t)(it + 1) * 64;
        nk0 = *(const uint4*)kp; nk1 = *(const uint4*)(kp + 8);
        nv0 = *(const uint4*)vp; nv1 = *(const uint4*)(vp + 8);
#pragma unroll
        for (int nt = 0; nt < 4; ++nt)
          namv[nt] = Acp[(it + 1) * 64 + nt * 16 + l16];
      }

      // ---- QK^T (b128 fragment reads) ----
      f4 s[4];
#pragma unroll
      for (int i = 0; i < 4; ++i) s[i] = (f4){0.f, 0.f, 0.f, 0.f};
#pragma unroll
      for (int ks = 0; ks < 2; ++ks) {
        H8 qk = ks ? qf1 : qf0;
#pragma unroll
        for (int nt = 0; nt < 4; ++nt) {
          H8 kf;
          kf.u4 = *(const uint4*)&K_lds[cur][(nt * 16 + l16) * LP + ks * 32 + quad * 8];
          s[nt] = __builtin_amdgcn_mfma_f32_16x16x32_f16(qk.h, kf.h, s[nt], 0, 0, 0);
        }
      }
      // ---- gate + S write (causal compare only on diagonal tile) ----
      const int m0 = it * 64;
      if (it == lt) {
#pragma unroll
        for (int nt = 0; nt < 4; ++nt) {
          const int mg = m0 + nt * 16 + l16;
          const float am = amv[nt];
#pragma unroll
          for (int r = 0; r < 4; ++r) {
            const int lg = l0 + w * 16 + quad * 4 + r;
            float val = (mg <= lg) ? s[nt][r] * __expf(alv[r] - am) * rc : 0.0f;
            S_lds[(w * 16 + quad * 4 + r) * LP + nt * 16 + l16] = f2h(val);
          }
        }
      } else {
#pragma unroll
        for (int nt = 0; nt < 4; ++nt) {
          const float am = amv[nt];
#pragma unroll
          for (int r = 0; r < 4; ++r) {
            float val = s[nt][r] * __expf(alv[r] - am) * rc;
            S_lds[(w * 16 + quad * 4 + r) * LP + nt * 16 + l16] = f2h(val);
          }
        }
      }
      // ---- PV (wave-private S rows; b128 reads) ----
#pragma unroll
      for (int ks = 0; ks < 2; ++ks) {
        H8 sa;
        sa.u4 = *(const uint4*)&S_lds[(w * 16 + l16) * LP + ks * 32 + quad * 8];
#pragma unroll
        for (int db = 0; db < 4; ++db) {
          H8 vb;
          vb.u4 = *(const uint4*)&V_lds[cur][(db * 16 + l16) * LP + ks * 32 + quad * 8];
          acc[db] = __builtin_amdgcn_mfma_f32_16x16x32_f16(sa.h, vb.h, acc[db], 0, 0, 0);
        }
      }
      // ---- stage next tile (b128) + one barrier ----
      if (more) {
        unsigned short* Kl = K_lds[cur ^ 1];
        unsigned short* Vl = V_lds[cur ^ 1];
        *(uint4*)&Kl[swo]     = nk0;
        *(uint4*)&Kl[swo + 8] = nk1;
        *(uint4*)&Vl[swo]     = nv0;
        *(uint4*)&Vl[swo + 8] = nv1;
#pragma unroll
        for (int nt = 0; nt < 4; ++nt) amv[nt] = namv[nt];
        __syncthreads();
        cur ^= 1;
      }
    }
  }

  // ---- write fp32 partials (zeros if this half had no work) ----
  float* pout = po + (size_t)s_ * (L_SEQ * HIDN);
#pragma unroll
  for (int r = 0; r < 4; ++r) {
    float* op = pout + (size_t)(l0 + w * 16 + quad * 4 + r) * HIDN + h * DHD + l16;
#pragma unroll
    for (int db = 0; db < 4; ++db)
      op[db * 16] = acc[db][r];
  }
}

// ------- reduce: po0+po1, RMSNorm over d=64, bf16 store --------------------
__global__ __launch_bounds__(256) void reduce_kernel(
    const float* __restrict__ po, const float* __restrict__ smallf,
    unsigned short* __restrict__ attn_out)
{
  const int l = blockIdx.x;
  const int t = threadIdx.x;
  const int col = t * 4;
  const float* p0 = po + (size_t)l * HIDN + col;
  const float* p1 = p0 + (size_t)L_SEQ * HIDN;
  f4 a = *(const f4*)p0;
  f4 b = *(const f4*)p1;
  f4 o = a + b;
  float p = o[0] * o[0] + o[1] * o[1] + o[2] * o[2] + o[3] * o[3];
#pragma unroll
  for (int off = 1; off < 16; off <<= 1) p += __shfl_xor(p, off);
  const float rn = rsqrtf(p * (1.0f / 64.0f) + 1.1920928955078125e-07f);
  const int d0 = col & 63;
  ushort4 st;
  st.x = f2b(o[0] * rn * smallf[9216 + d0]);
  st.y = f2b(o[1] * rn * smallf[9216 + d0 + 1]);
  st.z = f2b(o[2] * rn * smallf[9216 + d0 + 2]);
  st.w = f2b(o[3] * rn * smallf[9216 + d0 + 3]);
  *(ushort4*)&attn_out[(size_t)l * HIDN + col] = st;
}

extern "C" void kernel_launch(void* const* d_in, const int* in_sizes, int n_in,
                              void* d_out, int out_size, void* d_ws, size_t ws_size,
                              hipStream_t stream)
{
  (void)in_sizes; (void)n_in; (void)out_size; (void)ws_size;
  const void* hs        = d_in[0];
  // d_in[1] = attention_mask: deterministic causal triu — handled analytically
  const void* qkv_w     = d_in[2];
  const void* q_conv_w  = d_in[3];
  const void* q_conv_b  = d_in[4];
  const void* k_conv_w  = d_in[5];
  const void* k_conv_b  = d_in[6];
  const void* v_conv_w  = d_in[7];
  const void* v_conv_b  = d_in[8];
  const void* norm_w    = d_in[9];
  const void* A_log     = d_in[10];
  const void* dt_bias   = d_in[11];
  const void* dt_proj_w = d_in[12];
  const void* dt_proj_b = d_in[13];
  const void* o_w       = d_in[14];
  const void* ordc      = d_in[15];

  char* ws = (char*)d_ws;
  int* flag             = (int*)ws;                              // @0
  unsigned short* hs_b  = (unsigned short*)(ws + 256);           // 4,194,304
  unsigned short* qkvw_b= (unsigned short*)(ws + 4194560);       // 6,553,600 ([3200][1024])
  unsigned short* ow_b  = (unsigned short*)(ws + 10748160);      // 2,097,152
  float* smallf         = (float*)(ws + 12845312);               // 37,376
  float* qkvf           = (float*)(ws + 12882688);               // 26,214,400 ([2048][3200] f32)
  unsigned short* qc_h  = (unsigned short*)(ws + 39097088);      // 8,388,608 ([2048][2048] f16)
  float* Acum           = (float*)(ws + 47616768);               // 131,072
  unsigned short* attnb = (unsigned short*)(ws + 47747840);      // 4,194,304
  unsigned short* vt_h  = (unsigned short*)(ws + 51942144);      // 4,194,304
  float* po             = (float*)(ws + 56136448);               // 16,777,216 ([2][2048][1024] f32)

  prep_kernel<<<1024, 256, 0, stream>>>(
      hs, qkv_w, o_w, dt_proj_w,
      q_conv_w, q_conv_b, k_conv_w, k_conv_b, v_conv_w, v_conv_b,
      norm_w, A_log, dt_bias, dt_proj_b, ordc,
      hs_b, qkvw_b, ow_b, smallf, flag);

  gemm128<<<dim3(QKV_P / 128, L_SEQ / 128), 256, 0, stream>>>(
      hs_b, qkvw_b, qkvf, L_SEQ, QKV_P, HIDN);
  conv_kernel<<<4096 + 512 + 16, 256, 0, stream>>>(qkvf, smallf, qc_h, vt_h, Acum);
  attn_kernel<<<1024, 256, 0, stream>>>(qc_h, vt_h, Acum, smallf, po);
  reduce_kernel<<<L_SEQ, 256, 0, stream>>>(po, smallf, attnb);
  gemm_bt<1><<<dim3(HIDN / 64, L_SEQ / 64), 256, 0, stream>>>(
      attnb, ow_b, d_out, L_SEQ, HIDN, HIDN, flag);
}